// Round 2
// baseline (306.545 us; speedup 1.0000x reference)
//
#include <hip/hip_runtime.h>
#include <stdint.h>

// TopkActivation: per-row top-k (k=64) over H=32768 fp32, scatter into zeros.
// Persistent blocks (grid=256), 16 rows/block, software-pipelined:
//   - next row prefetched into registers while current row is histogrammed/
//     scanned/ranked/written
//   - raw s_barrier + lgkmcnt(0) (NOT __syncthreads) so prefetch loads and
//     output stores stay in flight across barriers (no vmcnt drain)
//   - winners marked in an LDS bitmap -> exactly ONE global store per element
// Radix-select on top 12 bits of an order-preserving monotonic key; tie
// semantics identical to jax.lax.top_k (equal values -> lower index first).

#define H_DIM    32768
#define NTHREADS 1024
#define VPT      (H_DIM / NTHREADS / 4)   // 8 float4 per thread
#define CAP      2048
#define NBINS    4096
#define NWORDS   (H_DIM / 32)             // 1024 bitmap words

typedef float f32x4 __attribute__((ext_vector_type(4)));

__device__ __forceinline__ uint32_t f2mono(float f) {
    uint32_t u = __float_as_uint(f);
    return (u & 0x80000000u) ? ~u : (u | 0x80000000u);
}
__device__ __forceinline__ float mono2f(uint32_t m) {
    uint32_t u = (m & 0x80000000u) ? (m & 0x7fffffffu) : ~m;
    return __uint_as_float(u);
}

// LDS-visibility barrier WITHOUT vmcnt drain: keeps global loads/stores in
// flight. All cross-thread state in this kernel lives in LDS.
__device__ __forceinline__ void BAR() {
    asm volatile("s_waitcnt lgkmcnt(0)" ::: "memory");
    __builtin_amdgcn_s_barrier();
}

__global__ __launch_bounds__(NTHREADS, 4)
void topk_kernel(const float* __restrict__ in, const int* __restrict__ kp,
                 float* __restrict__ out, int B)
{
    __shared__ uint32_t hist[NBINS];
    __shared__ uint32_t bitmap[NWORDS];
    __shared__ uint32_t wave_exc[16];
    __shared__ uint32_t s_b, s_g, s_cnt;
    __shared__ uint32_t s_ncand;
    __shared__ uint32_t cand_u[CAP];
    __shared__ uint32_t cand_i[CAP];

    const uint32_t t = threadIdx.x;
    const uint32_t k = (uint32_t)kp[0];

    int row = (int)blockIdx.x;
    const int rstride = (int)gridDim.x;

    // ---- prologue prefetch: first row -> registers
    f32x4 buf[VPT];
    if (row < B) {
        const f32x4* __restrict__ rin = (const f32x4*)(in + (size_t)row * H_DIM);
        #pragma unroll
        for (int i = 0; i < VPT; ++i)
            buf[i] = __builtin_nontemporal_load(&rin[t + i * NTHREADS]);
    }

    for (; row < B; row += rstride) {
        // ---- consume prefetch -> monotonic keys (waits on vmcnt via reg dep)
        uint32_t um[VPT][4];
        #pragma unroll
        for (int i = 0; i < VPT; ++i) {
            um[i][0] = f2mono(buf[i].x);
            um[i][1] = f2mono(buf[i].y);
            um[i][2] = f2mono(buf[i].z);
            um[i][3] = f2mono(buf[i].w);
        }
        // ---- issue next-row prefetch NOW; overlaps everything below
        {
            int nr = row + rstride;
            if (nr < B) {
                const f32x4* __restrict__ rin = (const f32x4*)(in + (size_t)nr * H_DIM);
                #pragma unroll
                for (int i = 0; i < VPT; ++i)
                    buf[i] = __builtin_nontemporal_load(&rin[t + i * NTHREADS]);
            }
        }

        BAR();  // previous iteration done with hist/bitmap/cand
        #pragma unroll
        for (int i = 0; i < NBINS / NTHREADS; ++i) hist[t + i * NTHREADS] = 0;
        bitmap[t] = 0;
        if (t == 0) s_ncand = 0;
        BAR();

        // ---- 12-bit histogram of monotonic-key top bits
        #pragma unroll
        for (int it = 0; it < VPT; ++it) {
            atomicAdd(&hist[um[it][0] >> 20], 1u);
            atomicAdd(&hist[um[it][1] >> 20], 1u);
            atomicAdd(&hist[um[it][2] >> 20], 1u);
            atomicAdd(&hist[um[it][3] >> 20], 1u);
        }
        BAR();

        // ---- boundary bin b: cumAbove(b) < k <= cumAbove(b) + hist[b]
        {
            uint32_t h0 = hist[4*t], h1 = hist[4*t+1], h2 = hist[4*t+2], h3 = hist[4*t+3];
            uint32_t s = h0 + h1 + h2 + h3;
            uint32_t lane = t & 63, wid = t >> 6;
            uint32_t v = s;
            #pragma unroll
            for (int off = 1; off < 64; off <<= 1) {   // inclusive suffix scan
                uint32_t o = __shfl_down(v, off);
                if (lane + off < 64) v += o;
            }
            if (lane == 0) wave_exc[wid] = v;
            BAR();
            if (t == 0) {                               // exclusive suffix over waves
                uint32_t acc = 0;
                for (int w = 15; w >= 0; --w) { uint32_t tw = wave_exc[w]; wave_exc[w] = acc; acc += tw; }
            }
            BAR();
            uint32_t cumIncl = v + wave_exc[wid];
            uint32_t Ech = cumIncl - s;                 // strictly-above count
            if (Ech < k && k <= Ech + s) {              // exactly one thread
                uint32_t gl = Ech;
                #pragma unroll
                for (int bb = 3; bb >= 0; --bb) {
                    uint32_t h = hist[4*t + bb];
                    if (gl + h >= k) { s_b = 4*t + (uint32_t)bb; s_g = gl; s_cnt = h; break; }
                    gl += h;
                }
            }
        }
        BAR();

        uint32_t prefix = s_b;
        uint32_t g      = s_g;
        uint32_t cnt    = s_cnt;
        uint32_t shift  = 20;

        // ---- rare fallback: refine until boundary-bin population fits CAP
        while (cnt > CAP && shift > 0) {
            uint32_t nshift = (shift >= 12) ? (shift - 12) : 0;
            uint32_t nbits  = shift - nshift;
            uint32_t nbins  = 1u << nbits;
            BAR();
            for (uint32_t i = t; i < nbins; i += NTHREADS) hist[i] = 0;
            BAR();
            #pragma unroll
            for (int it = 0; it < VPT; ++it) {
                #pragma unroll
                for (int c = 0; c < 4; ++c) {
                    uint32_t u = um[it][c];
                    if ((u >> shift) == prefix)
                        atomicAdd(&hist[(u >> nshift) & (nbins - 1)], 1u);
                }
            }
            BAR();
            if (t == 0) {
                uint32_t gl = g;
                for (int bb = (int)nbins - 1; bb >= 0; --bb) {
                    uint32_t h = hist[bb];
                    if (gl + h >= k) { s_b = (uint32_t)bb; s_g = gl; s_cnt = h; break; }
                    gl += h;
                }
            }
            BAR();
            prefix = (prefix << nbits) | s_b;
            g = s_g; cnt = s_cnt; shift = nshift;
        }

        // ---- collect boundary candidates (no stores yet)
        const uint32_t need = k - g;
        #pragma unroll
        for (int it = 0; it < VPT; ++it) {
            #pragma unroll
            for (int c = 0; c < 4; ++c) {
                uint32_t u = um[it][c];
                if ((u >> shift) == prefix) {
                    uint32_t p = atomicAdd(&s_ncand, 1u);
                    if (p < CAP) {
                        cand_u[p] = u;
                        cand_i[p] = (t + (uint32_t)it * NTHREADS) * 4u + (uint32_t)c;
                    }
                }
            }
        }
        BAR();

        // ---- rank candidates (value desc, index asc); mark winners in bitmap
        {
            uint32_t nc = s_ncand; if (nc > CAP) nc = CAP;
            for (uint32_t i = t; i < nc; i += NTHREADS) {
                uint32_t ui = cand_u[i], ii = cand_i[i];
                uint32_t rank = 0;
                for (uint32_t j = 0; j < nc; ++j) {
                    uint32_t uj = cand_u[j];
                    rank += (uj > ui || (uj == ui && cand_i[j] < ii)) ? 1u : 0u;
                }
                if (rank < need) atomicOr(&bitmap[ii >> 5], 1u << (ii & 31));
            }
        }
        BAR();

        // ---- single write pass: >prefix -> value; ==prefix -> bitmap; else 0
        {
            f32x4* __restrict__ rout = (f32x4*)(out + (size_t)row * H_DIM);
            #pragma unroll
            for (int it = 0; it < VPT; ++it) {
                f32x4 o;
                #pragma unroll
                for (int c = 0; c < 4; ++c) {
                    uint32_t u  = um[it][c];
                    uint32_t hi = u >> shift;
                    float val = 0.0f;
                    if (hi > prefix) {
                        val = mono2f(u);
                    } else if (hi == prefix) {
                        uint32_t ii = (t + (uint32_t)it * NTHREADS) * 4u + (uint32_t)c;
                        if ((bitmap[ii >> 5] >> (ii & 31)) & 1u) val = mono2f(u);
                    }
                    o[c] = val;
                }
                __builtin_nontemporal_store(o, &rout[t + it * NTHREADS]);
            }
        }
        // no trailing barrier: loop-top BAR orders LDS reuse; stores drain at
        // kernel end (no same-address re-store exists)
    }
}

extern "C" void kernel_launch(void* const* d_in, const int* in_sizes, int n_in,
                              void* d_out, int out_size, void* d_ws, size_t ws_size,
                              hipStream_t stream)
{
    const float* x  = (const float*)d_in[0];
    const int*   kp = (const int*)d_in[1];
    float* out = (float*)d_out;
    const int B = in_sizes[0] / H_DIM;
    int grid = B < 256 ? B : 256;
    hipLaunchKernelGGL(topk_kernel, dim3(grid), dim3(NTHREADS), 0, stream, x, kp, out, B);
}